// Round 11
// baseline (130.318 us; speedup 1.0000x reference)
//
#include <hip/hip_runtime.h>

#define B_ 4
#define C_ 128
#define N_ 4096          // H*W = 64*64
#define LOG2E 1.44269504088896340736f

typedef __attribute__((ext_vector_type(8))) __bf16 bf16x8;
typedef __attribute__((ext_vector_type(16))) float f32x16;

#define SWZ(n) (((n) & 15) << 4)

__device__ __forceinline__ unsigned short cvb(float x) {
    return __builtin_bit_cast(unsigned short, (__bf16)x);
}
__device__ __forceinline__ unsigned pk2(float lo, float hi) {
    return (unsigned)cvb(lo) | ((unsigned)cvb(hi) << 16);
}
__device__ __forceinline__ float bfu(unsigned short u) {
    return __builtin_bit_cast(float, (unsigned)u << 16);
}
// raw v_exp_f32 (2^x)
__device__ __forceinline__ float fexp2(float x) {
#if __has_builtin(__builtin_amdgcn_exp2f)
    return __builtin_amdgcn_exp2f(x);
#else
    float r;
    asm("v_exp_f32 %0, %1" : "=v"(r) : "v"(x));
    return r;
#endif
}
__device__ inline void gload_lds16(const void* g, void* l) {
    __builtin_amdgcn_global_load_lds(
        (const __attribute__((address_space(1))) unsigned int*)g,
        (__attribute__((address_space(3))) unsigned int*)l, 16, 0, 0);
}
// v_permlane32_swap_b32: a.hi32lanes <-> b.lo32lanes
__device__ __forceinline__ void plswapf(float& a, float& b) {
    asm volatile("v_permlane32_swap_b32 %0, %1" : "+v"(a), "+v"(b));
}
__device__ __forceinline__ void plswapu(unsigned& a, unsigned& b) {
    asm volatile("v_permlane32_swap_b32 %0, %1" : "+v"(a), "+v"(b));
}

// ============ weight convert f32 -> bf16, MFMA-FRAGMENT-ORDERED ============
__global__ __launch_bounds__(256) void k_wcvt(
        const float* pk, const float* lk, const float* pv, const float* lv,
        const float* t1, const float* nk, const float* nv,
        const float* q, const float* k, const float* v,
        const float* bpk, const float* blk, const float* bpv, const float* blv,
        const float* bnk, const float* bnv,
        unsigned short* Wk, unsigned short* Wv, unsigned short* Wt1,
        unsigned short* Wnow, unsigned short* Wq, unsigned short* Wkk,
        unsigned short* Wvv, float* bck, float* bcv, float* bcn) {
    int i = blockIdx.x * 256 + threadIdx.x;
    if (i < 22528) {
        int c = i;
        const float *s0, *s1 = nullptr;
        unsigned short* dst;
        int ks;                         // log2(K/16)
        if      (c < 4096)  { dst = Wk;   ks = 3; s0 = pk; s1 = lk; }
        else if (c < 8192)  { dst = Wv;   ks = 3; s0 = pv; s1 = lv; c -= 4096; }
        else if (c < 12288) { dst = Wt1;  ks = 4; s0 = t1;          c -= 8192; }
        else if (c < 16384) { dst = Wnow; ks = 3; s0 = nk; s1 = nv; c -= 12288; }
        else if (c < 18432) { dst = Wq;   ks = 3; s0 = q;           c -= 16384; }
        else if (c < 20480) { dst = Wkk;  ks = 3; s0 = k;           c -= 18432; }
        else                { dst = Wvv;  ks = 3; s0 = v;           c -= 20480; }
        int K = 16 << ks;
        int lane = c & 63, tile = c >> 6;
        int mt = tile >> ks, kt = tile & ((1 << ks) - 1);
        int row = mt * 32 + (lane & 31);
        int col = kt * 16 + (lane >> 5) * 8;
        const float* src = (s1 && row >= 128) ? (s1 + (size_t)(row - 128) * K + col)
                                              : (s0 + (size_t)row * K + col);
        unsigned short ov[8];
        #pragma unroll
        for (int j = 0; j < 8; ++j) ov[j] = cvb(src[j]);
        *(uint4*)(dst + (size_t)c * 8) = *(const uint4*)ov;
    }
    else if (i < 22784) { int j = i - 22528; bck[j] = j < 128 ? bpk[j] : blk[j - 128]; }
    else if (i < 23040) { int j = i - 22784; bcv[j] = j < 128 ? bpv[j] : blv[j - 128]; }
    else if (i < 23296) { int j = i - 23040; bcn[j] = j < 128 ? bnk[j] : bnv[j - 128]; }
}

// ============ fused pixelwise conv chain: 32-row tiles, 4 waves ============
template<int KSTEPS, int ROWB>
__device__ __forceinline__ f32x16 gtile(const char* Ab, int aChBase,
        const unsigned short* Wf, int mchunk, int nl, int h) {
    f32x16 acc;
    #pragma unroll
    for (int r = 0; r < 16; ++r) acc[r] = 0.f;
    const char* arow = Ab + nl * ROWB;
    const unsigned short* wb = Wf + ((size_t)mchunk * KSTEPS) * 512 + (nl + 32 * h) * 8;
    #pragma unroll
    for (int kk = 0; kk < KSTEPS; ++kk) {
        bf16x8 a = *(const bf16x8*)(arow + ((aChBase + kk * 32 + h * 16) ^ SWZ(nl)));
        bf16x8 wf = *(const bf16x8*)(wb + kk * 512);
        acc = __builtin_amdgcn_mfma_f32_32x32x16_bf16(a, wf, acc, 0, 0, 0);
    }
    return acc;
}

__device__ __forceinline__ void epi_lds(char* dst, int rowB, f32x16 acc,
        const float* bias, int m0, int nl, int h) {
    int m = m0 + nl;
    float bs = bias[m];
    #pragma unroll
    for (int r = 0; r < 16; ++r) {
        int n = (r & 3) + 8 * (r >> 2) + 4 * h;
        *(unsigned short*)(dst + n * rowB + ((m * 2) ^ SWZ(n))) =
            cvb(fmaxf(acc[r] + bs, 0.f));
    }
}

__device__ __forceinline__ void epi_nc(unsigned short* Y, f32x16 acc,
        const float* bias, float scale, int m0, int n0g, int b, int nl, int h) {
    int m = m0 + nl;
    float bs = bias[m];
    #pragma unroll
    for (int r = 0; r < 16; ++r) {
        int n = (r & 3) + 8 * (r >> 2) + 4 * h;
        Y[((size_t)b * N_ + n0g + n) * C_ + m] = cvb(fmaxf(acc[r] + bs, 0.f) * scale);
    }
}

__device__ __forceinline__ void epi_cn_b16(unsigned short* Y, f32x16 acc,
        const float* bias, int m0, int n0g, int b, int nl, int h) {
    int m = m0 + nl;
    float bs = bias[m];
    #pragma unroll
    for (int r2 = 0; r2 < 4; ++r2) {
        int nn = 8 * r2 + 4 * h;
        uint2 o;
        o.x = pk2(fmaxf(acc[4*r2+0] + bs, 0.f), fmaxf(acc[4*r2+1] + bs, 0.f));
        o.y = pk2(fmaxf(acc[4*r2+2] + bs, 0.f), fmaxf(acc[4*r2+3] + bs, 0.f));
        *(uint2*)(Y + ((size_t)b * C_ + m) * N_ + n0g + nn) = o;
    }
}

__device__ __forceinline__ void epi_cn_f32(float* Y, f32x16 acc,
        const float* bias, int m0, int n0g, int b, int nl, int h) {
    int m = m0 + nl;
    float bs = bias[m];
    #pragma unroll
    for (int r2 = 0; r2 < 4; ++r2) {
        int nn = 8 * r2 + 4 * h;
        float4 o;
        o.x = fmaxf(acc[4*r2+0] + bs, 0.f);
        o.y = fmaxf(acc[4*r2+1] + bs, 0.f);
        o.z = fmaxf(acc[4*r2+2] + bs, 0.f);
        o.w = fmaxf(acc[4*r2+3] + bs, 0.f);
        *(float4*)(Y + ((size_t)b * C_ + m) * N_ + n0g + nn) = o;
    }
}

// grid (N/32, B), 256 threads = 4 waves, wave w owns m-chunk w*32.
__global__ __launch_bounds__(256) void k_chain(
        const float* __restrict__ ev, const float* __restrict__ w_nb,
        const float* __restrict__ b_nb, const float* __restrict__ w_n1,
        const float* __restrict__ b_n1,
        const unsigned short* __restrict__ Wk, const unsigned short* __restrict__ Wv,
        const unsigned short* __restrict__ Wt1, const unsigned short* __restrict__ Wnow,
        const unsigned short* __restrict__ Wq, const unsigned short* __restrict__ Wkk,
        const unsigned short* __restrict__ Wvv,
        const float* __restrict__ bck, const float* __restrict__ bcv,
        const float* __restrict__ bt1, const float* __restrict__ bcn,
        const float* __restrict__ bq, const float* __restrict__ bk,
        const float* __restrict__ bv,
        unsigned short* __restrict__ Qt, unsigned short* __restrict__ Kb,
        unsigned short* __restrict__ Vb, float* __restrict__ NowV) {
    __shared__ char lds[57344];
    char* NEIGH = lds;
    char* KCAT  = lds + 16384;
    char* VCAT  = lds + 32768;
    char* NOWF  = lds + 49152;
    char* KEYN  = lds;
    char* VALN  = lds + 8192;
    char* NOWK  = lds + 16384;

    const int t = threadIdx.x, lane = t & 63, w = t >> 6;
    const int nl = lane & 31, h = lane >> 5;
    const int b = blockIdx.y;
    const int n0g = blockIdx.x * 32;
    const int m0 = w * 32;
    const int mc = w;

    {
        int n = t & 31, grp = t >> 5;
        const float* evb = ev + (size_t)b * 6 * N_ + n0g + n;
        float e0 = evb[0], e1 = evb[N_], e4 = evb[4*N_], e5 = evb[5*N_];
        float e2 = evb[2*N_], e3 = evb[3*N_];
        int och0 = grp * 32;
        #pragma unroll
        for (int i = 0; i < 32; i += 4) {
            float r_[4];
            #pragma unroll
            for (int j = 0; j < 4; ++j) {
                int o = och0 + i + j;
                float4 w4 = *(const float4*)(w_nb + o * 4);
                r_[j] = fmaxf(b_nb[o] + w4.x*e0 + w4.y*e1 + w4.z*e4 + w4.w*e5, 0.f);
            }
            uint2 val; val.x = pk2(r_[0], r_[1]); val.y = pk2(r_[2], r_[3]);
            *(uint2*)(NEIGH + n * 512 + (((och0 + i) * 2) ^ SWZ(n))) = val;
        }
        int o0 = grp * 16;
        #pragma unroll
        for (int i = 0; i < 16; i += 4) {
            float r_[4];
            #pragma unroll
            for (int j = 0; j < 4; ++j) {
                int o = o0 + i + j;
                float2 w2 = *(const float2*)(w_n1 + o * 2);
                r_[j] = fmaxf(b_n1[o] + w2.x*e2 + w2.y*e3, 0.f);
            }
            uint2 val; val.x = pk2(r_[0], r_[1]); val.y = pk2(r_[2], r_[3]);
            *(uint2*)(NOWF + n * 256 + (((o0 + i) * 2) ^ SWZ(n))) = val;
        }
    }
    __syncthreads();

    {
        f32x16 a0 = gtile<8, 512>(NEIGH, 0,   Wk, mc,     nl, h);
        f32x16 a1 = gtile<8, 512>(NEIGH, 0,   Wk, mc + 4, nl, h);
        f32x16 a2 = gtile<8, 512>(NEIGH, 256, Wv, mc,     nl, h);
        f32x16 a3 = gtile<8, 512>(NEIGH, 256, Wv, mc + 4, nl, h);
        epi_lds(KCAT, 512, a0, bck, m0,       nl, h);
        epi_lds(KCAT, 512, a1, bck, m0 + 128, nl, h);
        epi_lds(VCAT, 512, a2, bcv, m0,       nl, h);
        epi_lds(VCAT, 512, a3, bcv, m0 + 128, nl, h);
    }
    __syncthreads();

    {
        f32x16 a0 = gtile<16, 512>(KCAT, 0, Wt1, mc, nl, h);
        f32x16 a1 = gtile<16, 512>(VCAT, 0, Wt1, mc, nl, h);
        epi_lds(KEYN, 256, a0, bt1, m0, nl, h);
        epi_lds(VALN, 256, a1, bt1, m0, nl, h);
    }
    __syncthreads();

    {
        f32x16 a0 = gtile<8, 256>(NOWF, 0, Wnow, mc,     nl, h);
        f32x16 a1 = gtile<8, 256>(NOWF, 0, Wnow, mc + 4, nl, h);
        epi_lds(NOWK, 256, a0, bcn, m0, nl, h);
        epi_cn_f32(NowV, a1, bcn + 128, m0, n0g, b, nl, h);
    }
    __syncthreads();

    {
        f32x16 aq = gtile<8, 256>(KEYN, 0, Wq,  mc, nl, h);
        f32x16 ak = gtile<8, 256>(NOWK, 0, Wkk, mc, nl, h);
        f32x16 av = gtile<8, 256>(VALN, 0, Wvv, mc, nl, h);
        epi_nc(Qt, aq, bq, LOG2E, m0, n0g, b, nl, h);   // fold log2e into Q
        epi_nc(Kb, ak, bk, 1.0f,  m0, n0g, b, nl, h);
        epi_cn_b16(Vb, av, bv, m0, n0g, b, nl, h);
    }
}

// ---------------- flash attention partials -----------------------------------
// 2-wave blocks, 8-way m-split on grid (2048 blocks), K dbuf + V single buffer
// (24KB LDS -> 6 blocks/CU), 3-barrier counted-vmcnt schedule, permlane swaps,
// XCD-aware decode, raw v_exp_f32 softmax.
#define SPLIT 8
#define CHUNK 16          // m-tiles per block (SPLIT*CHUNK = 128)

__global__ __launch_bounds__(128) void k_flashp(
        const unsigned short* __restrict__ Qt, const unsigned short* __restrict__ Kt,
        const unsigned short* __restrict__ Vb,
        unsigned short* __restrict__ Opb, float* __restrict__ ML) {
    __shared__ char stgK[2][8192];               // K double buffer
    __shared__ char stgV[8192];                  // V single buffer
    const int t = threadIdx.x;
    const int lane = t & 63;
    const int nh = t >> 6;
    const int h = lane >> 5, nl = lane & 31;
    // combo = wgid&31 -> XCD = combo%8; all 64 ntiles of a combo share an XCD
    const int i_ = blockIdx.x;
    const int combo = i_ & 31;
    const int ntile = i_ >> 5;
    const int mp = combo >> 2, b = combo & 3;
    const int n0 = ntile * 64 + nh * 32;
    const size_t bo = (size_t)b * N_ * C_;

    // Q B-frags (hoisted, one-time gather)
    bf16x8 qf[8];
    {
        const char* qb = (const char*)(Qt + bo);
        #pragma unroll
        for (int kk = 0; kk < 8; ++kk)
            qf[kk] = *(const bf16x8*)(qb + (size_t)(n0 + nl) * 256 + kk*32 + h*16);
    }

    const char* ktb = (const char*)(Kt + bo);
    const char* vbb = (const char*)(Vb + bo);

    f32x16 oa[4];
    #pragma unroll
    for (int ss = 0; ss < 4; ++ss)
        #pragma unroll
        for (int r = 0; r < 16; ++r) oa[ss][r] = 0.f;
    float m_run = -1e30f, l_run = 0.f;

    const int swzK = (nl & 15) << 4;
    const int swzV = ((nl >> 1) & 7) << 4;

    auto stageK = [&](int tile, int ph) {          // wave nh=0, 8 loads
        const char* src = ktb + (size_t)tile * 8192;
        char* base = stgK[ph];
        #pragma unroll
        for (int ii = 0; ii < 8; ++ii) {
            int L = ii*1024 + lane*16;
            int T = L ^ (((L >> 8) & 15) << 4);
            gload_lds16(src + T, base + ii*1024);
        }
    };
    auto stageV = [&](int tile) {                  // wave nh=1, 8 loads
        const char* src = vbb + (size_t)tile * 64;
        #pragma unroll
        for (int ii = 0; ii < 8; ++ii) {
            int L = ii*1024 + lane*16;
            int T = L ^ (((L >> 7) & 7) << 4);
            int c = T >> 6, inner = T & 63;
            gload_lds16(src + (size_t)c * (N_*2) + inner, stgV + ii*1024);
        }
    };

    const int tb = mp * CHUNK;
    if (nh == 0) stageK(tb, 0);

    for (int it = 0; it < CHUNK; ++it) {
        int ph = it & 1;
        // top: issue V_i (wave1) and K_{i+1} (wave0)
        if (nh == 1) stageV(tb + it);
        else if (it + 1 < CHUNK) stageK(tb + it + 1, ph ^ 1);
        // wave0 waits for K_i (K_{i+1} stays in flight)
        if (nh == 0) {
            if (it + 1 < CHUNK) asm volatile("s_waitcnt vmcnt(8)" ::: "memory");
            else                asm volatile("s_waitcnt vmcnt(0)" ::: "memory");
        }
        __builtin_amdgcn_s_barrier();              // K_i visible
        __builtin_amdgcn_sched_barrier(0);
        const char* kb = stgK[ph];

        // QK^T: S^T tile (32m x 32n)
        f32x16 s;
        #pragma unroll
        for (int r = 0; r < 16; ++r) s[r] = 0.f;
        __builtin_amdgcn_s_setprio(1);
        #pragma unroll
        for (int kk = 0; kk < 8; ++kk) {
            int y = nl*256 + kk*32 + h*16;
            bf16x8 a = *(const bf16x8*)(kb + (y ^ swzK));
            s = __builtin_amdgcn_mfma_f32_32x32x16_bf16(a, qf[kk], s, 0, 0, 0);
        }
        __builtin_amdgcn_s_setprio(0);

        // online softmax over m (log2 domain), defer-max (T13)
        float tm = fmaxf(fmaxf(fmaxf(s[0], s[1]), fmaxf(s[2], s[3])),
                         fmaxf(fmaxf(s[4], s[5]), fmaxf(s[6], s[7])));
        float tm2 = fmaxf(fmaxf(fmaxf(s[8], s[9]), fmaxf(s[10], s[11])),
                          fmaxf(fmaxf(s[12], s[13]), fmaxf(s[14], s[15])));
        tm = fmaxf(tm, tm2);
        { float x = tm, y = tm; plswapf(x, y); tm = fmaxf(x, y); }
        if (!__all(tm <= m_run + 8.f)) {
            float mn = fmaxf(m_run, tm);
            float sc = fexp2(m_run - mn);
            m_run = mn;
            l_run *= sc;
            #pragma unroll
            for (int ss = 0; ss < 4; ++ss)
                #pragma unroll
                for (int r = 0; r < 16; ++r) oa[ss][r] *= sc;
        }
        float p[16];
        float ls = 0.f;
        #pragma unroll
        for (int r = 0; r < 16; ++r) { p[r] = fexp2(s[r] - m_run); ls += p[r]; }
        { float x = ls, y = ls; plswapf(x, y); ls = x + y; }
        l_run += ls;

        // pack P to bf16; build PV B-frags with 4 permlane swaps (register-only)
        unsigned pk_[8];
        #pragma unroll
        for (int q = 0; q < 8; ++q) pk_[q] = pk2(p[2*q], p[2*q+1]);
        unsigned a0 = pk_[0], a1 = pk_[1], b0 = pk_[2], b1 = pk_[3];
        plswapu(a0, b0); plswapu(a1, b1);    // kk2=0
        unsigned c0 = pk_[4], c1 = pk_[5], d0 = pk_[6], d1 = pk_[7];
        plswapu(c0, d0); plswapu(c1, d1);    // kk2=1
        typedef __attribute__((ext_vector_type(4))) unsigned u32x4;
        u32x4 uw0 = {a0, a1, b0, b1};
        u32x4 uw1 = {c0, c1, d0, d1};
        bf16x8 pf0 = __builtin_bit_cast(bf16x8, uw0);
        bf16x8 pf1 = __builtin_bit_cast(bf16x8, uw1);

        // wave1 waits for its V_i loads; barrier makes them visible to wave0
        if (nh == 1) asm volatile("s_waitcnt vmcnt(0)" ::: "memory");
        __builtin_amdgcn_s_barrier();              // V_i visible
        __builtin_amdgcn_sched_barrier(0);

        // PV: oa[ss] += V(32c x 16m) * P(16m x 32n), 2 k-steps
        __builtin_amdgcn_s_setprio(1);
        #pragma unroll
        for (int ss = 0; ss < 4; ++ss) {
            int y0 = (32*ss + nl)*64 + h*16;
            bf16x8 va0 = *(const bf16x8*)(stgV + (y0 ^ swzV));
            oa[ss] = __builtin_amdgcn_mfma_f32_32x32x16_bf16(va0, pf0, oa[ss], 0, 0, 0);
            bf16x8 va1 = *(const bf16x8*)(stgV + ((y0 + 32) ^ swzV));
            oa[ss] = __builtin_amdgcn_mfma_f32_32x32x16_bf16(va1, pf1, oa[ss], 0, 0, 0);
        }
        __builtin_amdgcn_s_setprio(0);

        __builtin_amdgcn_sched_barrier(0);
        __builtin_amdgcn_s_barrier();              // PV done before V overwrite
    }

    // store partials (Op as bf16)
    const size_t pb = (size_t)(mp * B_ + b) * 64 + ntile;
    if (h == 0) {
        ML[pb*128 +      nh*32 + nl] = m_run;
        ML[pb*128 + 64 + nh*32 + nl] = l_run;
    }
    unsigned short* dst = Opb + pb * 8192;
    #pragma unroll
    for (int ss = 0; ss < 4; ++ss)
        #pragma unroll
        for (int r = 0; r < 16; ++r) {
            int c = 32*ss + (r&3) + 8*(r>>2) + 4*h;
            dst[c*64 + nh*32 + nl] = cvb(oa[ss][r]);
        }
}

// ---------------- combine m-split partials + epilogue -----------------------
__global__ __launch_bounds__(256) void k_comb(const unsigned short* __restrict__ Opb,
        const float* __restrict__ ML, const float* __restrict__ NV,
        float* __restrict__ out) {
    const int t = threadIdx.x;
    const int ntile = blockIdx.x, b = blockIdx.y;
    const int n = t & 63, tq = t >> 6;
    float mj[SPLIT], lj[SPLIT], wj[SPLIT];
    #pragma unroll
    for (int j = 0; j < SPLIT; ++j) {
        size_t pb = (size_t)(j * B_ + b) * 64 + ntile;
        mj[j] = ML[pb*128 + n];
        lj[j] = ML[pb*128 + 64 + n];
    }
    float M = -1e30f;
    #pragma unroll
    for (int j = 0; j < SPLIT; ++j) M = fmaxf(M, mj[j]);
    float den = 0.f;
    #pragma unroll
    for (int j = 0; j < SPLIT; ++j) { wj[j] = fexp2(mj[j] - M); den += lj[j] * wj[j]; }
    float sc = 1e-4f / den;
    #pragma unroll 4
    for (int c = tq; c < C_; c += 4) {
        float v = 0.f;
        #pragma unroll
        for (int j = 0; j < SPLIT; ++j)
            v += bfu(Opb[((size_t)(j * B_ + b) * 64 + ntile) * 8192 + c*64 + n]) * wj[j];
        size_t gi = ((size_t)b * C_ + c) * N_ + ntile*64 + n;
        out[gi] = sc * v + NV[gi];
    }
}

extern "C" void kernel_launch(void* const* d_in, const int* in_sizes, int n_in,
                              void* d_out, int out_size, void* d_ws, size_t ws_size,
                              hipStream_t stream) {
    const float* ev   = (const float*)d_in[0];
    const float* w_nb = (const float*)d_in[1];  const float* b_nb = (const float*)d_in[2];
    const float* w_pk = (const float*)d_in[3];  const float* b_pk = (const float*)d_in[4];
    const float* w_pv = (const float*)d_in[5];  const float* b_pv = (const float*)d_in[6];
    const float* w_lk = (const float*)d_in[7];  const float* b_lk = (const float*)d_in[8];
    const float* w_lv = (const float*)d_in[9];  const float* b_lv = (const float*)d_in[10];
    const float* w_t1 = (const float*)d_in[11]; const float* b_t1 = (const float*)d_in[12];
    const float* w_n1 = (const float*)d_in[13]; const float* b_n1 = (const float*)d_in[14];
    const float* w_nk = (const float*)d_in[15]; const float* b_nk = (const float*)d_in[16];
    const float* w_nv = (const float*)d_in[17]; const float* b_nv = (const float*)d_in[18];
    const float* w_q  = (const float*)d_in[19]; const float* b_q  = (const float*)d_in[20];
    const float* w_k  = (const float*)d_in[21]; const float* b_k  = (const float*)d_in[22];
    const float* w_v  = (const float*)d_in[23]; const float* b_v  = (const float*)d_in[24];

    char* p = (char*)d_ws;
    unsigned short* Qt = (unsigned short*)p; p += (size_t)B_*N_*C_*2;
    unsigned short* Kb = (unsigned short*)p; p += (size_t)B_*N_*C_*2;
    unsigned short* Vb = (unsigned short*)p; p += (size_t)B_*C_*N_*2;
    float*          NowV = (float*)p;        p += (size_t)B_*C_*N_*4;
    unsigned short* Wk   = (unsigned short*)p; p += 32768*2;
    unsigned short* Wv   = (unsigned short*)p; p += 32768*2;
    unsigned short* Wt1  = (unsigned short*)p; p += 32768*2;
    unsigned short* Wnow = (unsigned short*)p; p += 32768*2;
    unsigned short* Wq   = (unsigned short*)p; p += 16384*2;
    unsigned short* Wkk  = (unsigned short*)p; p += 16384*2;
    unsigned short* Wvv  = (unsigned short*)p; p += 16384*2;
    float* bck = (float*)p; p += 256*4;
    float* bcv = (float*)p; p += 256*4;
    float* bcn = (float*)p; p += 256*4;
    p = (char*)(((size_t)p + 255) & ~(size_t)255);
    unsigned short* Opb = (unsigned short*)p; p += (size_t)SPLIT*B_*64*8192*2;  // 32 MB
    float* ML = (float*)p; p += (size_t)SPLIT*B_*64*128*4;                      // 1 MB

    k_wcvt<<<dim3(91), dim3(256), 0, stream>>>(
        w_pk, w_lk, w_pv, w_lv, w_t1, w_nk, w_nv, w_q, w_k, w_v,
        b_pk, b_lk, b_pv, b_lv, b_nk, b_nv,
        Wk, Wv, Wt1, Wnow, Wq, Wkk, Wvv, bck, bcv, bcn);

    k_chain<<<dim3(N_/32, B_), dim3(256), 0, stream>>>(
        ev, w_nb, b_nb, w_n1, b_n1,
        Wk, Wv, Wt1, Wnow, Wq, Wkk, Wvv,
        bck, bcv, b_t1, bcn, b_q, b_k, b_v,
        Qt, Kb, Vb, NowV);

    k_flashp<<<dim3(N_/64 * SPLIT * B_), dim3(128), 0, stream>>>(Qt, Kb, Vb, Opb, ML);

    k_comb<<<dim3(N_/64, B_), dim3(256), 0, stream>>>(Opb, ML, NowV, (float*)d_out);
}

// Round 12
// 84.730 us; speedup vs baseline: 1.5380x; 1.5380x over previous
//
#include <hip/hip_runtime.h>

#define B_ 4
#define C_ 128
#define N_ 4096          // H*W = 64*64
#define LOG2E 1.44269504088896340736f

typedef __attribute__((ext_vector_type(8))) __bf16 bf16x8;
typedef __attribute__((ext_vector_type(16))) float f32x16;

#define SWZ(n) (((n) & 15) << 4)

__device__ __forceinline__ unsigned short cvb(float x) {
    return __builtin_bit_cast(unsigned short, (__bf16)x);
}
__device__ __forceinline__ unsigned pk2(float lo, float hi) {
    return (unsigned)cvb(lo) | ((unsigned)cvb(hi) << 16);
}
__device__ __forceinline__ float bfu(unsigned short u) {
    return __builtin_bit_cast(float, (unsigned)u << 16);
}
// raw v_exp_f32 (2^x)
__device__ __forceinline__ float fexp2(float x) {
#if __has_builtin(__builtin_amdgcn_exp2f)
    return __builtin_amdgcn_exp2f(x);
#else
    float r;
    asm("v_exp_f32 %0, %1" : "=v"(r) : "v"(x));
    return r;
#endif
}
__device__ inline void gload_lds16(const void* g, void* l) {
    __builtin_amdgcn_global_load_lds(
        (const __attribute__((address_space(1))) unsigned int*)g,
        (__attribute__((address_space(3))) unsigned int*)l, 16, 0, 0);
}
// v_permlane32_swap_b32: a.hi32lanes <-> b.lo32lanes
__device__ __forceinline__ void plswapf(float& a, float& b) {
    asm volatile("v_permlane32_swap_b32 %0, %1" : "+v"(a), "+v"(b));
}
__device__ __forceinline__ void plswapu(unsigned& a, unsigned& b) {
    asm volatile("v_permlane32_swap_b32 %0, %1" : "+v"(a), "+v"(b));
}

// ============ weight convert f32 -> bf16, MFMA-FRAGMENT-ORDERED ============
__global__ __launch_bounds__(256) void k_wcvt(
        const float* pk, const float* lk, const float* pv, const float* lv,
        const float* t1, const float* nk, const float* nv,
        const float* q, const float* k, const float* v,
        const float* bpk, const float* blk, const float* bpv, const float* blv,
        const float* bnk, const float* bnv,
        unsigned short* Wk, unsigned short* Wv, unsigned short* Wt1,
        unsigned short* Wnow, unsigned short* Wq, unsigned short* Wkk,
        unsigned short* Wvv, float* bck, float* bcv, float* bcn) {
    int i = blockIdx.x * 256 + threadIdx.x;
    if (i < 22528) {
        int c = i;
        const float *s0, *s1 = nullptr;
        unsigned short* dst;
        int ks;                         // log2(K/16)
        if      (c < 4096)  { dst = Wk;   ks = 3; s0 = pk; s1 = lk; }
        else if (c < 8192)  { dst = Wv;   ks = 3; s0 = pv; s1 = lv; c -= 4096; }
        else if (c < 12288) { dst = Wt1;  ks = 4; s0 = t1;          c -= 8192; }
        else if (c < 16384) { dst = Wnow; ks = 3; s0 = nk; s1 = nv; c -= 12288; }
        else if (c < 18432) { dst = Wq;   ks = 3; s0 = q;           c -= 16384; }
        else if (c < 20480) { dst = Wkk;  ks = 3; s0 = k;           c -= 18432; }
        else                { dst = Wvv;  ks = 3; s0 = v;           c -= 20480; }
        int K = 16 << ks;
        int lane = c & 63, tile = c >> 6;
        int mt = tile >> ks, kt = tile & ((1 << ks) - 1);
        int row = mt * 32 + (lane & 31);
        int col = kt * 16 + (lane >> 5) * 8;
        const float* src = (s1 && row >= 128) ? (s1 + (size_t)(row - 128) * K + col)
                                              : (s0 + (size_t)row * K + col);
        unsigned short ov[8];
        #pragma unroll
        for (int j = 0; j < 8; ++j) ov[j] = cvb(src[j]);
        *(uint4*)(dst + (size_t)c * 8) = *(const uint4*)ov;
    }
    else if (i < 22784) { int j = i - 22528; bck[j] = j < 128 ? bpk[j] : blk[j - 128]; }
    else if (i < 23040) { int j = i - 22784; bcv[j] = j < 128 ? bpv[j] : blv[j - 128]; }
    else if (i < 23296) { int j = i - 23040; bcn[j] = j < 128 ? bnk[j] : bnv[j - 128]; }
}

// ============ fused pixelwise conv chain: 32-row tiles, 4 waves, 48KB LDS ====
template<int KSTEPS, int ROWB>
__device__ __forceinline__ f32x16 gtile(const char* Ab, int aChBase,
        const unsigned short* Wf, int mchunk, int nl, int h) {
    f32x16 acc;
    #pragma unroll
    for (int r = 0; r < 16; ++r) acc[r] = 0.f;
    const char* arow = Ab + nl * ROWB;
    const unsigned short* wb = Wf + ((size_t)mchunk * KSTEPS) * 512 + (nl + 32 * h) * 8;
    #pragma unroll
    for (int kk = 0; kk < KSTEPS; ++kk) {
        bf16x8 a = *(const bf16x8*)(arow + ((aChBase + kk * 32 + h * 16) ^ SWZ(nl)));
        bf16x8 wf = *(const bf16x8*)(wb + kk * 512);
        acc = __builtin_amdgcn_mfma_f32_32x32x16_bf16(a, wf, acc, 0, 0, 0);
    }
    return acc;
}

__device__ __forceinline__ void epi_lds(char* dst, int rowB, f32x16 acc,
        const float* bias, int m0, int nl, int h) {
    int m = m0 + nl;
    float bs = bias[m];
    #pragma unroll
    for (int r = 0; r < 16; ++r) {
        int n = (r & 3) + 8 * (r >> 2) + 4 * h;
        *(unsigned short*)(dst + n * rowB + ((m * 2) ^ SWZ(n))) =
            cvb(fmaxf(acc[r] + bs, 0.f));
    }
}

__device__ __forceinline__ void epi_nc(unsigned short* Y, f32x16 acc,
        const float* bias, float scale, int m0, int n0g, int b, int nl, int h) {
    int m = m0 + nl;
    float bs = bias[m];
    #pragma unroll
    for (int r = 0; r < 16; ++r) {
        int n = (r & 3) + 8 * (r >> 2) + 4 * h;
        Y[((size_t)b * N_ + n0g + n) * C_ + m] = cvb(fmaxf(acc[r] + bs, 0.f) * scale);
    }
}

__device__ __forceinline__ void epi_cn_b16(unsigned short* Y, f32x16 acc,
        const float* bias, int m0, int n0g, int b, int nl, int h) {
    int m = m0 + nl;
    float bs = bias[m];
    #pragma unroll
    for (int r2 = 0; r2 < 4; ++r2) {
        int nn = 8 * r2 + 4 * h;
        uint2 o;
        o.x = pk2(fmaxf(acc[4*r2+0] + bs, 0.f), fmaxf(acc[4*r2+1] + bs, 0.f));
        o.y = pk2(fmaxf(acc[4*r2+2] + bs, 0.f), fmaxf(acc[4*r2+3] + bs, 0.f));
        *(uint2*)(Y + ((size_t)b * C_ + m) * N_ + n0g + nn) = o;
    }
}

// grid (N/32, B), 256 threads = 4 waves, wave w owns m-chunk w*32.
__global__ __launch_bounds__(256) void k_chain(
        const float* __restrict__ ev, const float* __restrict__ w_nb,
        const float* __restrict__ b_nb, const float* __restrict__ w_n1,
        const float* __restrict__ b_n1,
        const unsigned short* __restrict__ Wk, const unsigned short* __restrict__ Wv,
        const unsigned short* __restrict__ Wt1, const unsigned short* __restrict__ Wnow,
        const unsigned short* __restrict__ Wq, const unsigned short* __restrict__ Wkk,
        const unsigned short* __restrict__ Wvv,
        const float* __restrict__ bck, const float* __restrict__ bcv,
        const float* __restrict__ bt1, const float* __restrict__ bcn,
        const float* __restrict__ bq, const float* __restrict__ bk,
        const float* __restrict__ bv,
        unsigned short* __restrict__ Qt, unsigned short* __restrict__ Kb,
        unsigned short* __restrict__ Vb, unsigned short* __restrict__ NowVb) {
    __shared__ char lds[49152];
    char* NEIGH = lds;                 // 16K [S1 write, S2 read, dies]
    char* KCAT  = lds + 16384;         // 16K [S2 write, S3 read, dies]
    char* VCAT  = lds + 32768;         // 16K [S2 write, S3 read, dies]
    char* KEYN  = lds;                 //  8K over NEIGH[0:8K]  [S3w, S6r]
    char* VALN  = lds + 8192;          //  8K over NEIGH[8K:]   [S3w, S6r]
    char* NOWF  = lds + 16384;         //  8K over KCAT[0:8K]   [S4w, S5r]
    char* NOWK  = lds + 24576;         //  8K over KCAT[8K:]    [S5w, S6r]

    const int t = threadIdx.x, lane = t & 63, w = t >> 6;
    const int nl = lane & 31, h = lane >> 5;
    const int b = blockIdx.y;
    const int n0g = blockIdx.x * 32;
    const int m0 = w * 32;
    const int mc = w;

    // ---- S1: neigh -> LDS ; nowf -> 4 packed uint2 REGISTERS ----
    uint2 nf[4];
    {
        int n = t & 31, grp = t >> 5;          // 8 thread-groups per pixel
        const float* evb = ev + (size_t)b * 6 * N_ + n0g + n;
        float e0 = evb[0], e1 = evb[N_], e4 = evb[4*N_], e5 = evb[5*N_];
        float e2 = evb[2*N_], e3 = evb[3*N_];
        int och0 = grp * 32;
        #pragma unroll
        for (int i = 0; i < 32; i += 4) {
            float r_[4];
            #pragma unroll
            for (int j = 0; j < 4; ++j) {
                int o = och0 + i + j;
                float4 w4 = *(const float4*)(w_nb + o * 4);
                r_[j] = fmaxf(b_nb[o] + w4.x*e0 + w4.y*e1 + w4.z*e4 + w4.w*e5, 0.f);
            }
            uint2 val; val.x = pk2(r_[0], r_[1]); val.y = pk2(r_[2], r_[3]);
            *(uint2*)(NEIGH + n * 512 + (((och0 + i) * 2) ^ SWZ(n))) = val;
        }
        int o0 = grp * 16;
        #pragma unroll
        for (int i2 = 0; i2 < 4; ++i2) {
            float r_[4];
            #pragma unroll
            for (int j = 0; j < 4; ++j) {
                int o = o0 + i2 * 4 + j;
                float2 w2 = *(const float2*)(w_n1 + o * 2);
                r_[j] = fmaxf(b_n1[o] + w2.x*e2 + w2.y*e3, 0.f);
            }
            nf[i2].x = pk2(r_[0], r_[1]); nf[i2].y = pk2(r_[2], r_[3]);
        }
    }
    __syncthreads();

    // ---- S2: kcat = [Wpk;Wlk] @ neigh_pro ; vcat = [Wpv;Wlv] @ neigh_lat ----
    {
        f32x16 a0 = gtile<8, 512>(NEIGH, 0,   Wk, mc,     nl, h);
        f32x16 a1 = gtile<8, 512>(NEIGH, 0,   Wk, mc + 4, nl, h);
        f32x16 a2 = gtile<8, 512>(NEIGH, 256, Wv, mc,     nl, h);
        f32x16 a3 = gtile<8, 512>(NEIGH, 256, Wv, mc + 4, nl, h);
        epi_lds(KCAT, 512, a0, bck, m0,       nl, h);
        epi_lds(KCAT, 512, a1, bck, m0 + 128, nl, h);
        epi_lds(VCAT, 512, a2, bcv, m0,       nl, h);
        epi_lds(VCAT, 512, a3, bcv, m0 + 128, nl, h);
    }
    __syncthreads();

    // ---- S3: keyn = Wt1 @ kcat ; valn = Wt1 @ vcat (K=256), over NEIGH ----
    {
        f32x16 a0 = gtile<16, 512>(KCAT, 0, Wt1, mc, nl, h);
        f32x16 a1 = gtile<16, 512>(VCAT, 0, Wt1, mc, nl, h);
        epi_lds(KEYN, 256, a0, bt1, m0, nl, h);
        epi_lds(VALN, 256, a1, bt1, m0, nl, h);
    }
    __syncthreads();          // KCAT/VCAT dead from here

    // ---- S4: spill nowf registers to LDS (over KCAT) ----
    {
        int n = t & 31, grp = t >> 5;
        int o0 = grp * 16;
        #pragma unroll
        for (int i2 = 0; i2 < 4; ++i2)
            *(uint2*)(NOWF + n * 256 + (((o0 + i2 * 4) * 2) ^ SWZ(n))) = nf[i2];
    }
    __syncthreads();

    // ---- S5: nowk = Wnk @ nowf (LDS) ; nowv -> NowVb (bf16 (C,N)) ----
    {
        f32x16 a0 = gtile<8, 256>(NOWF, 0, Wnow, mc,     nl, h);
        f32x16 a1 = gtile<8, 256>(NOWF, 0, Wnow, mc + 4, nl, h);
        epi_lds(NOWK, 256, a0, bcn, m0, nl, h);
        epi_cn_b16(NowVb, a1, bcn + 128, m0, n0g, b, nl, h);
    }
    __syncthreads();

    // ---- S6: q -> Qt(N,C) ; k -> Kb(N,C) ; v -> Vb(C,N) ----
    {
        f32x16 aq = gtile<8, 256>(KEYN, 0, Wq,  mc, nl, h);
        f32x16 ak = gtile<8, 256>(NOWK, 0, Wkk, mc, nl, h);
        f32x16 av = gtile<8, 256>(VALN, 0, Wvv, mc, nl, h);
        epi_nc(Qt, aq, bq, LOG2E, m0, n0g, b, nl, h);   // fold log2e into Q
        epi_nc(Kb, ak, bk, 1.0f,  m0, n0g, b, nl, h);
        epi_cn_b16(Vb, av, bv, m0, n0g, b, nl, h);
    }
}

// ---------------- flash attention partials (r10-identical) -------------------
#define SPLIT 4
#define CHUNK 32          // m-tiles per block

__global__ __launch_bounds__(128) void k_flashp(
        const unsigned short* __restrict__ Qt, const unsigned short* __restrict__ Kt,
        const unsigned short* __restrict__ Vb,
        unsigned short* __restrict__ Opb, float* __restrict__ ML) {
    __shared__ char stg[2][16384];               // dbuf x (K 8KB | V 8KB)
    const int t = threadIdx.x;
    const int lane = t & 63;
    const int nh = t >> 6;
    const int h = lane >> 5, nl = lane & 31;
    // XCD-aware decode: xcd = wgid%8 gets combos {xcd, xcd+8}
    const int i_ = blockIdx.x;
    const int mpb = (i_ & 7) + 8 * ((i_ >> 3) & 1);
    const int ntile = i_ >> 4;
    const int mp = mpb >> 2, b = mpb & 3;
    const int n0 = ntile * 64 + nh * 32;
    const size_t bo = (size_t)b * N_ * C_;

    // Q B-frags (hoisted, one-time gather)
    bf16x8 qf[8];
    {
        const char* qb = (const char*)(Qt + bo);
        #pragma unroll
        for (int kk = 0; kk < 8; ++kk)
            qf[kk] = *(const bf16x8*)(qb + (size_t)(n0 + nl) * 256 + kk*32 + h*16);
    }

    const char* ktb = (const char*)(Kt + bo);
    const char* vbb = (const char*)(Vb + bo);

    f32x16 oa[4];
    #pragma unroll
    for (int ss = 0; ss < 4; ++ss)
        #pragma unroll
        for (int r = 0; r < 16; ++r) oa[ss][r] = 0.f;
    float m_run = -1e30f, l_run = 0.f;

    const int swzK = (nl & 15) << 4;
    const int swzV = ((nl >> 1) & 7) << 4;

    // wave nh=0 stages K tile (8KB, 8 loads), wave nh=1 stages V tile
    auto stage = [&](int tile, int ph) {
        char* base = stg[ph];
        if (nh == 0) {
            const char* src = ktb + (size_t)tile * 8192;
            #pragma unroll
            for (int ii = 0; ii < 8; ++ii) {
                int L = ii*1024 + lane*16;
                int T = L ^ (((L >> 8) & 15) << 4);
                gload_lds16(src + T, base + ii*1024);
            }
        } else {
            const char* src = vbb + (size_t)tile * 64;
            #pragma unroll
            for (int ii = 0; ii < 8; ++ii) {
                int L = ii*1024 + lane*16;
                int T = L ^ (((L >> 7) & 7) << 4);
                int c = T >> 6, inner = T & 63;
                gload_lds16(src + (size_t)c * (N_*2) + inner, base + 8192 + ii*1024);
            }
        }
    };

    const int tb = mp * CHUNK;
    stage(tb, 0);
    stage(tb + 1, 1);

    for (int it = 0; it < CHUNK; ++it) {
        int ph = it & 1;
        if (it < CHUNK - 1) asm volatile("s_waitcnt vmcnt(8)" ::: "memory");
        else                asm volatile("s_waitcnt vmcnt(0)" ::: "memory");
        __builtin_amdgcn_s_barrier();
        __builtin_amdgcn_sched_barrier(0);
        const char* kb = stg[ph];
        const char* vb = kb + 8192;

        // QK^T: S^T tile (32m x 32n)
        f32x16 s;
        #pragma unroll
        for (int r = 0; r < 16; ++r) s[r] = 0.f;
        __builtin_amdgcn_s_setprio(1);
        #pragma unroll
        for (int kk = 0; kk < 8; ++kk) {
            int y = nl*256 + kk*32 + h*16;
            bf16x8 a = *(const bf16x8*)(kb + (y ^ swzK));
            s = __builtin_amdgcn_mfma_f32_32x32x16_bf16(a, qf[kk], s, 0, 0, 0);
        }
        __builtin_amdgcn_s_setprio(0);

        // online softmax over m (log2 domain), defer-max (T13)
        float tm = fmaxf(fmaxf(fmaxf(s[0], s[1]), fmaxf(s[2], s[3])),
                         fmaxf(fmaxf(s[4], s[5]), fmaxf(s[6], s[7])));
        float tm2 = fmaxf(fmaxf(fmaxf(s[8], s[9]), fmaxf(s[10], s[11])),
                          fmaxf(fmaxf(s[12], s[13]), fmaxf(s[14], s[15])));
        tm = fmaxf(tm, tm2);
        { float x = tm, y = tm; plswapf(x, y); tm = fmaxf(x, y); }
        if (!__all(tm <= m_run + 8.f)) {
            float mn = fmaxf(m_run, tm);
            float sc = fexp2(m_run - mn);
            m_run = mn;
            l_run *= sc;
            #pragma unroll
            for (int ss = 0; ss < 4; ++ss)
                #pragma unroll
                for (int r = 0; r < 16; ++r) oa[ss][r] *= sc;
        }
        float p[16];
        float ls = 0.f;
        #pragma unroll
        for (int r = 0; r < 16; ++r) { p[r] = fexp2(s[r] - m_run); ls += p[r]; }
        { float x = ls, y = ls; plswapf(x, y); ls = x + y; }
        l_run += ls;

        // pack P to bf16; build PV B-frags with 4 permlane swaps
        unsigned pk_[8];
        #pragma unroll
        for (int q = 0; q < 8; ++q) pk_[q] = pk2(p[2*q], p[2*q+1]);
        unsigned a0 = pk_[0], a1 = pk_[1], b0 = pk_[2], b1 = pk_[3];
        plswapu(a0, b0); plswapu(a1, b1);    // kk2=0
        unsigned c0 = pk_[4], c1 = pk_[5], d0 = pk_[6], d1 = pk_[7];
        plswapu(c0, d0); plswapu(c1, d1);    // kk2=1
        typedef __attribute__((ext_vector_type(4))) unsigned u32x4;
        u32x4 uw0 = {a0, a1, b0, b1};
        u32x4 uw1 = {c0, c1, d0, d1};
        bf16x8 pf0 = __builtin_bit_cast(bf16x8, uw0);
        bf16x8 pf1 = __builtin_bit_cast(bf16x8, uw1);

        // PV: oa[ss] += V(32c x 16m) * P(16m x 32n), 2 k-steps
        __builtin_amdgcn_s_setprio(1);
        #pragma unroll
        for (int ss = 0; ss < 4; ++ss) {
            int y0 = (32*ss + nl)*64 + h*16;
            bf16x8 va0 = *(const bf16x8*)(vb + (y0 ^ swzV));
            oa[ss] = __builtin_amdgcn_mfma_f32_32x32x16_bf16(va0, pf0, oa[ss], 0, 0, 0);
            bf16x8 va1 = *(const bf16x8*)(vb + ((y0 + 32) ^ swzV));
            oa[ss] = __builtin_amdgcn_mfma_f32_32x32x16_bf16(va1, pf1, oa[ss], 0, 0, 0);
        }
        __builtin_amdgcn_s_setprio(0);

        __builtin_amdgcn_sched_barrier(0);
        __builtin_amdgcn_s_barrier();        // both waves done reading stg[ph]
        if (it + 2 < CHUNK) stage(tb + it + 2, ph);
    }

    // store partials (Op as bf16)
    const size_t pb = (size_t)(mp * B_ + b) * 64 + ntile;
    if (h == 0) {
        ML[pb*128 +      nh*32 + nl] = m_run;
        ML[pb*128 + 64 + nh*32 + nl] = l_run;
    }
    unsigned short* dst = Opb + pb * 8192;
    #pragma unroll
    for (int ss = 0; ss < 4; ++ss)
        #pragma unroll
        for (int r = 0; r < 16; ++r) {
            int c = 32*ss + (r&3) + 8*(r>>2) + 4*h;
            dst[c*64 + nh*32 + nl] = cvb(oa[ss][r]);
        }
}

// ---------------- combine m-split partials + epilogue -----------------------
__global__ __launch_bounds__(256) void k_comb(const unsigned short* __restrict__ Opb,
        const float* __restrict__ ML, const unsigned short* __restrict__ NVb,
        float* __restrict__ out) {
    const int t = threadIdx.x;
    const int ntile = blockIdx.x, b = blockIdx.y;
    const int n = t & 63, tq = t >> 6;
    float mj[SPLIT], lj[SPLIT], wj[SPLIT];
    #pragma unroll
    for (int j = 0; j < SPLIT; ++j) {
        size_t pb = (size_t)(j * B_ + b) * 64 + ntile;
        mj[j] = ML[pb*128 + n];
        lj[j] = ML[pb*128 + 64 + n];
    }
    float M = -1e30f;
    #pragma unroll
    for (int j = 0; j < SPLIT; ++j) M = fmaxf(M, mj[j]);
    float den = 0.f;
    #pragma unroll
    for (int j = 0; j < SPLIT; ++j) { wj[j] = fexp2(mj[j] - M); den += lj[j] * wj[j]; }
    float sc = 1e-4f / den;
    #pragma unroll 4
    for (int c = tq; c < C_; c += 4) {
        float v = 0.f;
        #pragma unroll
        for (int j = 0; j < SPLIT; ++j)
            v += bfu(Opb[((size_t)(j * B_ + b) * 64 + ntile) * 8192 + c*64 + n]) * wj[j];
        size_t gi = ((size_t)b * C_ + c) * N_ + ntile*64 + n;
        out[gi] = sc * v + bfu(NVb[gi]);
    }
}

extern "C" void kernel_launch(void* const* d_in, const int* in_sizes, int n_in,
                              void* d_out, int out_size, void* d_ws, size_t ws_size,
                              hipStream_t stream) {
    const float* ev   = (const float*)d_in[0];
    const float* w_nb = (const float*)d_in[1];  const float* b_nb = (const float*)d_in[2];
    const float* w_pk = (const float*)d_in[3];  const float* b_pk = (const float*)d_in[4];
    const float* w_pv = (const float*)d_in[5];  const float* b_pv = (const float*)d_in[6];
    const float* w_lk = (const float*)d_in[7];  const float* b_lk = (const float*)d_in[8];
    const float* w_lv = (const float*)d_in[9];  const float* b_lv = (const float*)d_in[10];
    const float* w_t1 = (const float*)d_in[11]; const float* b_t1 = (const float*)d_in[12];
    const float* w_n1 = (const float*)d_in[13]; const float* b_n1 = (const float*)d_in[14];
    const float* w_nk = (const float*)d_in[15]; const float* b_nk = (const float*)d_in[16];
    const float* w_nv = (const float*)d_in[17]; const float* b_nv = (const float*)d_in[18];
    const float* w_q  = (const float*)d_in[19]; const float* b_q  = (const float*)d_in[20];
    const float* w_k  = (const float*)d_in[21]; const float* b_k  = (const float*)d_in[22];
    const float* w_v  = (const float*)d_in[23]; const float* b_v  = (const float*)d_in[24];

    char* p = (char*)d_ws;
    unsigned short* Qt = (unsigned short*)p; p += (size_t)B_*N_*C_*2;
    unsigned short* Kb = (unsigned short*)p; p += (size_t)B_*N_*C_*2;
    unsigned short* Vb = (unsigned short*)p; p += (size_t)B_*C_*N_*2;
    unsigned short* NowVb = (unsigned short*)p; p += (size_t)B_*C_*N_*2;   // bf16
    unsigned short* Wk   = (unsigned short*)p; p += 32768*2;
    unsigned short* Wv   = (unsigned short*)p; p += 32768*2;
    unsigned short* Wt1  = (unsigned short*)p; p += 32768*2;
    unsigned short* Wnow = (unsigned short*)p; p += 32768*2;
    unsigned short* Wq   = (unsigned short*)p; p += 16384*2;
    unsigned short* Wkk  = (unsigned short*)p; p += 16384*2;
    unsigned short* Wvv  = (unsigned short*)p; p += 16384*2;
    float* bck = (float*)p; p += 256*4;
    float* bcv = (float*)p; p += 256*4;
    float* bcn = (float*)p; p += 256*4;
    p = (char*)(((size_t)p + 255) & ~(size_t)255);
    unsigned short* Opb = (unsigned short*)p; p += (size_t)SPLIT*B_*64*8192*2;  // 16 MB
    float* ML = (float*)p; p += (size_t)SPLIT*B_*64*128*4;                      // 512 KB

    k_wcvt<<<dim3(91), dim3(256), 0, stream>>>(
        w_pk, w_lk, w_pv, w_lv, w_t1, w_nk, w_nv, w_q, w_k, w_v,
        b_pk, b_lk, b_pv, b_lv, b_nk, b_nv,
        Wk, Wv, Wt1, Wnow, Wq, Wkk, Wvv, bck, bcv, bcn);

    k_chain<<<dim3(N_/32, B_), dim3(256), 0, stream>>>(
        ev, w_nb, b_nb, w_n1, b_n1,
        Wk, Wv, Wt1, Wnow, Wq, Wkk, Wvv,
        bck, bcv, b_t1, bcn, b_q, b_k, b_v,
        Qt, Kb, Vb, NowVb);

    k_flashp<<<dim3(N_/64 * SPLIT * B_), dim3(128), 0, stream>>>(Qt, Kb, Vb, Opb, ML);

    k_comb<<<dim3(N_/64, B_), dim3(256), 0, stream>>>(Opb, ML, NowVb, (float*)d_out);
}